// Round 11
// baseline (322.307 us; speedup 1.0000x reference)
//
#include <hip/hip_runtime.h>

#define RANK    64
#define N_GAMMA 7
#define N_ALPHA 64
#define WLEN    (N_GAMMA * N_ALPHA)   // 448 floats in W

__device__ __forceinline__ float dot4(const float4 a, const float4 b) {
    return fmaf(a.x, b.x, fmaf(a.y, b.y, fmaf(a.z, b.z, a.w * b.w)));
}

// Fused: each block computes W = gamma^T @ alpha (448 floats) into LDS, then
// waves stream x. One wave handles 4 consecutive rows (448 contiguous float4);
// lane l, iter i reads float4 #(i*64+l): coalesced 1 KiB per instruction.
__global__ void __launch_bounds__(256) cp_fused_kernel(
    const float4* __restrict__ x4,     // [N/4 groups][448 float4]
    const float* __restrict__ beta,    // [1]
    const float* __restrict__ gamma,   // [64,7]
    const float* __restrict__ alpha,   // [64,64]
    float* __restrict__ y,             // [N]
    int nGroups) {
    __shared__ float w_lds[WLEN];

    // --- Stage 1: W[i][j] = sum_r gamma[r][i]*alpha[r][j] (per-block, ~1 us) ---
    for (int t = threadIdx.x; t < WLEN; t += blockDim.x) {
        int i = t >> 6;       // 0..6
        int j = t & 63;       // 0..63
        float s = 0.f;
#pragma unroll
        for (int r = 0; r < RANK; ++r)
            s = fmaf(gamma[r * N_GAMMA + i], alpha[r * N_ALPHA + j], s);
        w_lds[t] = s;
    }
    __syncthreads();

    const int lane = threadIdx.x & 63;

    // Per-lane W fragments: iter i uses floats 4*((i*64+lane)%112).. of W-row.
    float4 wv[7];
#pragma unroll
    for (int i = 0; i < 7; ++i) {
        int j = i * 64 + lane;                 // 0..447
        wv[i] = *(const float4*)&w_lds[4 * (j % 112)];
    }
    const float beta0 = beta[0];

    // Lane-invariant row-straddle predicates (iters 1,3,5 span two rows;
    // iters 0,2,4,6 are statically single-row for every lane).
    const bool p1 = lane < 48;   // iter1: row0 if j<112
    const bool p3 = lane < 32;   // iter3: row1 if j<224
    const bool p5 = lane < 16;   // iter5: row2 if j<336

    const int wave   = blockIdx.x * (blockDim.x >> 6) + (threadIdx.x >> 6);
    const int nWaves = gridDim.x * (blockDim.x >> 6);

    for (int g = wave; g < nGroups; g += nWaves) {
        const float4* __restrict__ p = x4 + (size_t)g * 448;
        float4 v0 = p[0 * 64 + lane];
        float4 v1 = p[1 * 64 + lane];
        float4 v2 = p[2 * 64 + lane];
        float4 v3 = p[3 * 64 + lane];
        float4 v4 = p[4 * 64 + lane];
        float4 v5 = p[5 * 64 + lane];
        float4 v6 = p[6 * 64 + lane];
        float d0 = dot4(v0, wv[0]);
        float d1 = dot4(v1, wv[1]);
        float d2 = dot4(v2, wv[2]);
        float d3 = dot4(v3, wv[3]);
        float d4 = dot4(v4, wv[4]);
        float d5 = dot4(v5, wv[5]);
        float d6 = dot4(v6, wv[6]);
        float a0 = d0 + (p1 ? d1 : 0.f);
        float a1 = d2 + (p1 ? 0.f : d1) + (p3 ? d3 : 0.f);
        float a2 = d4 + (p3 ? 0.f : d3) + (p5 ? d5 : 0.f);
        float a3 = d6 + (p5 ? 0.f : d5);

        // Fold-and-pack reduction: 10 shfl instead of 24.
        float c0 = a0 + __shfl_xor(a0, 32, 64);
        float c1 = a1 + __shfl_xor(a1, 32, 64);
        float c2 = a2 + __shfl_xor(a2, 32, 64);
        float c3 = a3 + __shfl_xor(a3, 32, 64);
        float d01 = (lane & 32) ? c1 : c0;      // rows 0|1 in lane halves
        float d23 = (lane & 32) ? c3 : c2;      // rows 2|3 in lane halves
        d01 += __shfl_xor(d01, 16, 64);
        d23 += __shfl_xor(d23, 16, 64);
        float f = (lane & 16) ? d23 : d01;      // rows 0,2,1,3 in 16-lane groups
        f += __shfl_xor(f, 8, 64);
        f += __shfl_xor(f, 4, 64);
        f += __shfl_xor(f, 2, 64);
        f += __shfl_xor(f, 1, 64);
        // lane 0 -> row0, lane 16 -> row2, lane 32 -> row1, lane 48 -> row3
        if ((lane & 15) == 0) {
            int r = ((lane >> 4) & 1) * 2 + ((lane >> 5) & 1);
            y[g * 4 + r] = beta0 + f;
        }
    }
}

extern "C" void kernel_launch(void* const* d_in, const int* in_sizes, int n_in,
                              void* d_out, int out_size, void* d_ws, size_t ws_size,
                              hipStream_t stream) {
    const float* x     = (const float*)d_in[0];   // [N,7,64]
    const float* beta  = (const float*)d_in[1];   // [1]
    const float* gamma = (const float*)d_in[2];   // [64,7]
    const float* alpha = (const float*)d_in[3];   // [64,64]
    float* y = (float*)d_out;

    const int n = in_sizes[0] / WLEN;             // 131072
    const int nGroups = n / 4;                    // 32768

    const int blocks = 2048;                      // 8192 waves, 4 groups each
    cp_fused_kernel<<<blocks, 256, 0, stream>>>((const float4*)x, beta, gamma, alpha, y, nGroups);
}